// Round 1
// 304.637 us; speedup vs baseline: 1.0194x; 1.0194x over previous
//
#include <hip/hip_runtime.h>
#include <hip/hip_bf16.h>

typedef __hip_bfloat16 bf16;
typedef short bf16x8_t __attribute__((ext_vector_type(8)));  // 8 bf16 = 4 VGPRs
typedef float f32x4_t __attribute__((ext_vector_type(4)));

#define NTOK 8192
#define INF  1024
#define OUTF 1024
#define GS   8
#define KTOT (INF + INF * GS)  // 9216

union b8u { bf16 h[8]; bf16x8_t v; };
union b4u { bf16 h[4]; ushort2 v2[2]; };

// ---------------- fused prep (R6 access patterns, verbatim; one dispatch) ----------
// Blocks [0, PA): A[n,k] = bf16[ silu(x) | exp(-|x-grid_g|) ]  -- R6 prep_a body.
// Blocks [PA, PA+PB): B[o,k] = bf16[ bw | sw*ss ]              -- R6 prep_b body.
#define PA ((NTOK * INF) / 256)       // 32768 blocks
#define PB ((OUTF * INF * 2) / 256)   //  8192 blocks

__global__ __launch_bounds__(256) void prep_fused(const float* __restrict__ x,
                                                  const float* __restrict__ bw,
                                                  const float* __restrict__ sw,
                                                  const float* __restrict__ ss,
                                                  const float* __restrict__ grid,
                                                  bf16* __restrict__ A,
                                                  bf16* __restrict__ B) {
  const int b = blockIdx.x;
  if (b < PA) {
    const int idx = b * 256 + threadIdx.x;         // n*INF + i
    const int i = idx & (INF - 1);
    const int n = idx >> 10;
    const float xv = x[idx];
    const float s = xv / (1.0f + __expf(-xv));     // SiLU
    const size_t rowb = (size_t)n * KTOT;
    A[rowb + i] = __float2bfloat16(s);
    b8u kn;
    #pragma unroll
    for (int g = 0; g < 8; ++g) {
      const float gv = grid[g];                    // row 0 == row i (broadcast_to)
      kn.h[g] = __float2bfloat16(__expf(-fabsf(xv - gv)));  // sigma = 1
    }
    *(bf16x8_t*)(A + rowb + INF + (size_t)i * 8) = kn.v;   // 16B lane-contiguous
  } else {
    const int tid = (b - PA) * 256 + threadIdx.x;  // 0 .. OUTF*INF*2-1
    const int o = tid >> 11;                       // 2048 threads per o-row
    const int r = tid & 2047;                      // i*2 + half
    const float4 w4 = ((const float4*)sw)[tid];    // 4 of the 8 g-values of (o,i)
    const float sc = ss[tid >> 1];
    b4u r4;
    r4.h[0] = __float2bfloat16(w4.x * sc);
    r4.h[1] = __float2bfloat16(w4.y * sc);
    r4.h[2] = __float2bfloat16(w4.z * sc);
    r4.h[3] = __float2bfloat16(w4.w * sc);
    const size_t rowb = (size_t)o * KTOT;
    *(ushort2*)(B + rowb + INF + (size_t)r * 4)     = r4.v2[0];  // 8B contiguous
    *(ushort2*)(B + rowb + INF + (size_t)r * 4 + 2) = r4.v2[1];
    if ((tid & 1) == 0)                            // even lanes: base weight
      B[rowb + (r >> 1)] = __float2bfloat16(bw[tid >> 1]);
  }
}

// ---------------- GEMM v2: C[M,N] = A[M,K] * B[N,K]^T --------------------------------
// 8-phase-family schedule (T3+T4+T5, guide §5/§5.5) adapted to N=1024:
//   BM=256 BN=128 BK=64, 512 thr = 8 waves (4M x 2N), per-wave 64x64 (m97 fragment
//   logic verbatim). Grid 8x32 = 256 blocks = exactly 1 block/CU.
//   3-deep LDS ring (144 KB) -> prefetch distance 2 -> boundary wait is vmcnt(6),
//   NEVER vmcnt(0) in steady state (T4: counted vmcnt is the whole gain, m218).
//   2 phases per K-tile, 16 MFMA each (template density), setprio around MFMA (T5),
//   XOR LDS swizzle both-sides involution carried from the verified R3 kernel.
// Hazard ledger:
//   - phase-p stages write buf[(kt+2)%3] = buf last READ in iter kt-1 phase 2; those
//     reads complete before kt-1's lgkmcnt(0)+final barrier -> 2 barriers of slack.
//   - boundary vmcnt(6): 6 newest outstanding = tile kt+2's loads; everything older
//     (tile kt+1's 6) retired -> next iter's ds_reads are safe after the barrier.
//   - tail: kt >= NT-2 issues no stages -> boundary drains with vmcnt(0) (2 iters).
#define BM 256
#define BN 128
#define BK 64
#define NT (KTOT / BK)            // 144
#define LDSA (BM * BK * 2)        // 32768 B
#define LDSB (BN * BK * 2)        // 16384 B
#define LDSBUF (LDSA + LDSB)      // 49152 B

__global__ __launch_bounds__(512) void gemm_bt2(const bf16* __restrict__ A,
                                                const bf16* __restrict__ B,
                                                float* __restrict__ C) {
  __shared__ __align__(16) char smem[3 * LDSBUF];   // 144 KB ring
  const int t = threadIdx.x;
  const int lane = t & 63;
  const int w = t >> 6;            // wave 0..7
  const int wm = (w >> 1) * 64;    // 0,64,128,192
  const int wn = (w & 1) * 64;     // 0,64
  const int bc = blockIdx.x;       // N tile (0..7)
  const int br = blockIdx.y;       // M tile (0..31)

  // staging: 512 thr x 16B = 8 KB per inst = 64 rows of 64 k (128 B/row).
  // XOR swizzle: slot (srow, c) holds global k-chunk c ^ (srow&7); row&7 invariant
  // under +64-row inst strides, so one swizzled source offset serves all insts.
  const int srow = t >> 3;                         // 0..63
  const int scol = ((t & 7) ^ (srow & 7)) * 8;     // swizzled source k-offset (elems)
  const bf16* gA = A + (size_t)(br * BM + srow) * KTOT + scol;
  const bf16* gB = B + (size_t)(bc * BN + srow) * KTOT + scol;
  const int wb = w * 1024;                         // wave's 64 lanes x 16B

  // fragment addressing (verbatim from verified kernel)
  const int frow = lane & 15;
  const int fk = (lane >> 4) * 8;
  const int fsw = frow & 7;
  const int swk0 = (((0  + fk) >> 3) ^ fsw) * 8;   // kk=0  swizzled elem offset
  const int swk1 = (((32 + fk) >> 3) ^ fsw) * 8;   // kk=32

  f32x4_t acc[4][4] = {};

#define STAGE_A(b_, i_, kt_) \
  __builtin_amdgcn_global_load_lds( \
      (const __attribute__((address_space(1))) void*)(gA + (size_t)(i_) * 64 * KTOT + (size_t)(kt_) * BK), \
      (__attribute__((address_space(3))) void*)(smem + (b_) * LDSBUF + (i_) * 8192 + wb), 16, 0, 0)
#define STAGE_B(b_, i_, kt_) \
  __builtin_amdgcn_global_load_lds( \
      (const __attribute__((address_space(1))) void*)(gB + (size_t)(i_) * 64 * KTOT + (size_t)(kt_) * BK), \
      (__attribute__((address_space(3))) void*)(smem + (b_) * LDSBUF + LDSA + (i_) * 8192 + wb), 16, 0, 0)

  // prologue: tile 0 -> buf0, tile 1 -> buf1 (12 loads in flight)
  STAGE_A(0, 0, 0); STAGE_A(0, 1, 0); STAGE_A(0, 2, 0); STAGE_A(0, 3, 0);
  STAGE_B(0, 0, 0); STAGE_B(0, 1, 0);
  STAGE_A(1, 0, 1); STAGE_A(1, 1, 1); STAGE_A(1, 2, 1); STAGE_A(1, 3, 1);
  STAGE_B(1, 0, 1); STAGE_B(1, 1, 1);
  asm volatile("s_waitcnt vmcnt(6)" ::: "memory");   // tile 0 resident
  __builtin_amdgcn_s_barrier();

  int cb = 0;
  for (int kt = 0; kt < NT; ++kt) {
    const bf16* sAc = (const bf16*)(smem + cb * LDSBUF);
    const bf16* sBc = (const bf16*)(smem + cb * LDSBUF + LDSA);
    const int pb = (cb == 0) ? 2 : cb - 1;           // (kt+2)%3
    const bool pf = kt < NT - 2;

    bf16x8_t af[4], bfr[4];

    // ---------------- phase 1: kk = 0 ----------------
    #pragma unroll
    for (int i = 0; i < 4; ++i)
      af[i] = *(const bf16x8_t*)(sAc + (wm + i * 16 + frow) * BK + swk0);
    #pragma unroll
    for (int j = 0; j < 4; ++j)
      bfr[j] = *(const bf16x8_t*)(sBc + (wn + j * 16 + frow) * BK + swk0);
    if (pf) { STAGE_A(pb, 0, kt + 2); STAGE_A(pb, 1, kt + 2); STAGE_A(pb, 2, kt + 2); }
    __builtin_amdgcn_s_barrier();
    asm volatile("s_waitcnt lgkmcnt(0)" ::: "memory");
    __builtin_amdgcn_sched_barrier(0);
    __builtin_amdgcn_s_setprio(1);
    #pragma unroll
    for (int i = 0; i < 4; ++i)
      #pragma unroll
      for (int j = 0; j < 4; ++j)
        acc[i][j] = __builtin_amdgcn_mfma_f32_16x16x32_bf16(af[i], bfr[j], acc[i][j], 0, 0, 0);
    __builtin_amdgcn_s_setprio(0);
    __builtin_amdgcn_s_barrier();

    // ---------------- phase 2: kk = 32 ----------------
    #pragma unroll
    for (int i = 0; i < 4; ++i)
      af[i] = *(const bf16x8_t*)(sAc + (wm + i * 16 + frow) * BK + swk1);
    #pragma unroll
    for (int j = 0; j < 4; ++j)
      bfr[j] = *(const bf16x8_t*)(sBc + (wn + j * 16 + frow) * BK + swk1);
    if (pf) { STAGE_A(pb, 3, kt + 2); STAGE_B(pb, 0, kt + 2); STAGE_B(pb, 1, kt + 2); }
    __builtin_amdgcn_s_barrier();
    asm volatile("s_waitcnt lgkmcnt(0)" ::: "memory");
    __builtin_amdgcn_sched_barrier(0);
    __builtin_amdgcn_s_setprio(1);
    #pragma unroll
    for (int i = 0; i < 4; ++i)
      #pragma unroll
      for (int j = 0; j < 4; ++j)
        acc[i][j] = __builtin_amdgcn_mfma_f32_16x16x32_bf16(af[i], bfr[j], acc[i][j], 0, 0, 0);
    __builtin_amdgcn_s_setprio(0);
    // tile boundary: counted wait — tile kt+1's loads are strictly older than the
    // 6 issued this iteration, so vmcnt(6) retires them without draining the pipe.
    if (pf) asm volatile("s_waitcnt vmcnt(6)" ::: "memory");
    else    asm volatile("s_waitcnt vmcnt(0)" ::: "memory");
    __builtin_amdgcn_s_barrier();

    cb = (cb == 2) ? 0 : cb + 1;
  }

  // epilogue: D mapping col = lane&15, row = (lane>>4)*4 + reg  [m89/m91]
  const int ccol = bc * BN + wn + frow;
  const int crow0 = br * BM + wm + (lane >> 4) * 4;
  #pragma unroll
  for (int i = 0; i < 4; ++i)
    #pragma unroll
    for (int r = 0; r < 4; ++r) {
      float* cp = C + (size_t)(crow0 + i * 16 + r) * OUTF + ccol;
      #pragma unroll
      for (int j = 0; j < 4; ++j)
        cp[j * 16] = acc[i][j][r];
    }
#undef STAGE_A
#undef STAGE_B
}

// ---------------- fallback (ws too small): naive, correctness-only ----------------
__global__ __launch_bounds__(256) void naive_kern(const float* __restrict__ x,
                                                  const float* __restrict__ bw,
                                                  const float* __restrict__ sw,
                                                  const float* __restrict__ ss,
                                                  const float* __restrict__ grid,
                                                  float* __restrict__ out) {
  const int idx = blockIdx.x * 256 + threadIdx.x;  // n*OUTF + o
  const int o = idx & (OUTF - 1);
  const int n = idx >> 10;
  float acc = 0.f;
  for (int i = 0; i < INF; ++i) {
    const float xv = x[n * INF + i];
    const float s = xv / (1.f + __expf(-xv));
    acc += s * bw[o * INF + i];
    const float sc = ss[o * INF + i];
    #pragma unroll
    for (int g = 0; g < 8; ++g) {
      const float gv = grid[i * 8 + g];
      acc += __expf(-fabsf(xv - gv)) * sw[(size_t)(o * INF + i) * 8 + g] * sc;
    }
  }
  out[idx] = acc;
}

extern "C" void kernel_launch(void* const* d_in, const int* in_sizes, int n_in,
                              void* d_out, int out_size, void* d_ws, size_t ws_size,
                              hipStream_t stream) {
  const float* x    = (const float*)d_in[0];
  const float* bw   = (const float*)d_in[1];
  const float* sw   = (const float*)d_in[2];
  const float* ss   = (const float*)d_in[3];
  const float* grid = (const float*)d_in[4];
  float* out = (float*)d_out;

  const size_t needA = (size_t)NTOK * KTOT * sizeof(bf16);  // ~151 MB
  const size_t needB = (size_t)OUTF * KTOT * sizeof(bf16);  // ~19 MB

  if (ws_size >= needA + needB) {
    bf16* A = (bf16*)d_ws;
    bf16* B = (bf16*)((char*)d_ws + needA);
    prep_fused<<<PA + PB, 256, 0, stream>>>(x, bw, sw, ss, grid, A, B);
    dim3 g(OUTF / BN, NTOK / BM);  // (8, 32) = 256 blocks = 1/CU
    gemm_bt2<<<g, 512, 0, stream>>>(A, B, out);
  } else {
    naive_kern<<<(NTOK * OUTF) / 256, 256, 0, stream>>>(x, bw, sw, ss, grid, out);
  }
}